// Round 2
// baseline (241.391 us; speedup 1.0000x reference)
//
#include <hip/hip_runtime.h>

// RetrosynthesisAttention: additive (Bahdanau) attention, B=16, N=M=D=U=256, fp32.
//   enc_proj = enc @ W1 + b1; dec_proj = dec @ W2 + b2
//   logits[b,n,m] = sum_u v[u]*tanh(enc_proj[b,m,u]+dec_proj[b,n,u]) + v_b
//   attn = softmax_m(logits);  ctx[b,n,d] = sum_m attn*enc[b,m,d]
//
// tanh(x) = 1 - 2/(exp2(K*x)+1), K = 2*log2(e); the constants sum_u v_u and
// v_b cancel in softmax -> effective logit = -2 * sum_u v_u * rcp(exp2(.)+1).
// Projections stored PRE-SCALED by K in natural [rows][U] layout so the attn
// inner loop reads ep as sequential float4 (L1-cached lines).

constexpr float KSC   = 2.8853900817779268f;  // 2*log2(e)
constexpr float LOG2E = 1.4426950408889634f;

struct F4 { float v[4]; };
__device__ __forceinline__ F4 ld4(const float* p) {
    float4 t = *(const float4*)p;
    F4 r; r.v[0] = t.x; r.v[1] = t.y; r.v[2] = t.z; r.v[3] = t.w; return r;
}

// ---------------- Kernel A: both projection GEMMs.
// Zero LDS, zero barriers: 32-row x 64-col tile, 256 threads, 2x4 micro-tile.
// X rows and W rows are read as float4 from global; W float4s are shared by
// 16-lane groups (broadcast) and all reuse hits L1/L2.
__global__ __launch_bounds__(256) void proj_kernel(
    const float* __restrict__ enc, const float* __restrict__ dec,
    const float* __restrict__ W1,  const float* __restrict__ b1,
    const float* __restrict__ W2,  const float* __restrict__ b2,
    float* __restrict__ encP,      // [B*M][U] = [4096][256], scaled by KSC
    float* __restrict__ decS)      // [B*N][U] = [4096][256], scaled by KSC
{
    const int tid = threadIdx.x;
    const int tu  = tid >> 4;             // 0..15 -> u group (4 u's)
    const int tm  = tid & 15;             // 0..15 -> row pair
    const int u0  = blockIdx.x * 64;      // 4 u-blocks
    const int row0 = blockIdx.y * 32;     // 256 row-blocks over 8192 flat rows
    const bool is_enc = row0 < 4096;
    const float* X    = is_enc ? enc : dec;
    const float* W    = is_enc ? W1  : W2;
    const float* bias = is_enc ? b1  : b2;
    float* OUT        = is_enc ? encP : decS;
    const int rb   = is_enc ? row0 : row0 - 4096;
    const int ucol = u0 + (tu << 2);
    const int r0   = rb + (tm << 1);

    const float* x0 = X + r0 * 256;
    const float* x1 = x0 + 256;
    const float* wp = W + ucol;

    float acc[2][4] = {};
    #pragma unroll 2
    for (int d4 = 0; d4 < 256; d4 += 4) {
        F4 xa0 = ld4(x0 + d4);
        F4 xa1 = ld4(x1 + d4);
        F4 wr[4];
        #pragma unroll
        for (int jj = 0; jj < 4; ++jj) wr[jj] = ld4(wp + (d4 + jj) * 256);
        #pragma unroll
        for (int jj = 0; jj < 4; ++jj) {
            #pragma unroll
            for (int j = 0; j < 4; ++j) {
                acc[0][j] = fmaf(xa0.v[jj], wr[jj].v[j], acc[0][j]);
                acc[1][j] = fmaf(xa1.v[jj], wr[jj].v[j], acc[1][j]);
            }
        }
    }

    F4 bb = ld4(bias + ucol);
    #pragma unroll
    for (int i = 0; i < 2; ++i) {
        float4 o;
        o.x = KSC * (acc[i][0] + bb.v[0]);
        o.y = KSC * (acc[i][1] + bb.v[1]);
        o.z = KSC * (acc[i][2] + bb.v[2]);
        o.w = KSC * (acc[i][3] + bb.v[3]);
        *(float4*)&OUT[(r0 + i) * 256 + ucol] = o;
    }
}

// ---------------- Kernel B: fused tanh-logits + softmax + context.
// Block = (b, n-tile of 4), 512 threads (8 waves). Threads 0-255 own n-pair
// {0,1}, threads 256-511 own {2,3}; both halves stream the same ep lines (L1).
// Grid 1024 blocks * 8 waves = 32 waves/CU -> 100% theoretical occupancy.
__global__ __launch_bounds__(512) void attn_kernel(
    const float* __restrict__ enc,   // [B][M][D]
    const float* __restrict__ encP,  // [B*M][U], scaled
    const float* __restrict__ decS,  // [B*N][U], scaled
    const float* __restrict__ vw,    // [U]
    float* __restrict__ out_ctx,     // [B][N][D]
    float* __restrict__ out_attn)    // [B][N][M]
{
    __shared__ float dps[4][256];
    __shared__ float vws[256];
    __shared__ float attn_s[4][256];
    __shared__ float red[2][4][4];

    const int tid = threadIdx.x;
    const int b   = blockIdx.y;
    const int n0  = blockIdx.x * 4;
    const int h   = tid >> 8;        // half: 0 -> t{0,1}, 1 -> t{2,3}
    const int m   = tid & 255;

    {   // stage dec_proj rows (4x256) and v
        const float* dsrc = decS + (b * 256 + n0) * 256;
        ((float*)dps)[tid]       = dsrc[tid];
        ((float*)dps)[tid + 512] = dsrc[tid + 512];
        if (tid < 256) vws[tid] = vw[tid];
    }
    __syncthreads();

    const int t0 = h << 1, t1 = t0 | 1;
    const float* ep = encP + (b * 256 + m) * 256;

    float a0 = 0.f, a1 = 0.f;
    #pragma unroll 2
    for (int u0 = 0; u0 < 256; u0 += 4) {
        F4 ev = ld4(ep + u0);
        F4 d0 = ld4(&dps[t0][u0]);
        F4 d1 = ld4(&dps[t1][u0]);
        F4 vv = ld4(&vws[u0]);
        #pragma unroll
        for (int j = 0; j < 4; ++j) {
            const float e0 = __builtin_amdgcn_exp2f(ev.v[j] + d0.v[j]);
            a0 = fmaf(vv.v[j], __builtin_amdgcn_rcpf(e0 + 1.0f), a0);
            const float e1 = __builtin_amdgcn_exp2f(ev.v[j] + d1.v[j]);
            a1 = fmaf(vv.v[j], __builtin_amdgcn_rcpf(e1 + 1.0f), a1);
        }
    }
    float l0 = -2.f * a0, l1 = -2.f * a1;

    // ---- softmax over m: each t's 256 m's live in 4 waves of one half
    const int lane = tid & 63, wv_ = (tid >> 6) & 3;
    float x0 = l0, x1 = l1;
    #pragma unroll
    for (int off = 32; off > 0; off >>= 1) {
        x0 = fmaxf(x0, __shfl_xor(x0, off));
        x1 = fmaxf(x1, __shfl_xor(x1, off));
    }
    if (lane == 0) { red[0][t0][wv_] = x0; red[0][t1][wv_] = x1; }
    __syncthreads();
    const float mx0 = fmaxf(fmaxf(red[0][t0][0], red[0][t0][1]),
                            fmaxf(red[0][t0][2], red[0][t0][3]));
    const float mx1 = fmaxf(fmaxf(red[0][t1][0], red[0][t1][1]),
                            fmaxf(red[0][t1][2], red[0][t1][3]));
    float p0 = __builtin_amdgcn_exp2f((l0 - mx0) * LOG2E);
    float p1 = __builtin_amdgcn_exp2f((l1 - mx1) * LOG2E);
    float s0 = p0, s1 = p1;
    #pragma unroll
    for (int off = 32; off > 0; off >>= 1) {
        s0 += __shfl_xor(s0, off);
        s1 += __shfl_xor(s1, off);
    }
    if (lane == 0) { red[1][t0][wv_] = s0; red[1][t1][wv_] = s1; }
    __syncthreads();
    const float sum0 = (red[1][t0][0] + red[1][t0][1]) + (red[1][t0][2] + red[1][t0][3]);
    const float sum1 = (red[1][t1][0] + red[1][t1][1]) + (red[1][t1][2] + red[1][t1][3]);
    const float w0 = p0 / sum0;
    const float w1 = p1 / sum1;
    attn_s[t0][m] = w0;
    attn_s[t1][m] = w1;
    out_attn[(b * 256 + n0 + t0) * 256 + m] = w0;
    out_attn[(b * 256 + n0 + t1) * 256 + m] = w1;
    __syncthreads();

    // ---- context: ctx[t][d] = sum_m attn[t][m] * enc[b][m][d]; d = m (=tid&255)
    const float* eb = enc + b * 65536 + m;
    float c0 = 0.f, c1 = 0.f;
    #pragma unroll 8
    for (int mm = 0; mm < 256; ++mm) {
        const float ev = eb[mm * 256];
        c0 = fmaf(attn_s[t0][mm], ev, c0);
        c1 = fmaf(attn_s[t1][mm], ev, c1);
    }
    out_ctx[(b * 256 + n0 + t0) * 256 + m] = c0;
    out_ctx[(b * 256 + n0 + t1) * 256 + m] = c1;
}

extern "C" void kernel_launch(void* const* d_in, const int* in_sizes, int n_in,
                              void* d_out, int out_size, void* d_ws, size_t ws_size,
                              hipStream_t stream) {
    const float* enc = (const float*)d_in[0];
    const float* dec = (const float*)d_in[1];
    const float* W1  = (const float*)d_in[2];
    const float* b1  = (const float*)d_in[3];
    const float* W2  = (const float*)d_in[4];
    const float* b2  = (const float*)d_in[5];
    const float* vw  = (const float*)d_in[6];
    // d_in[7] (v_b) cancels in softmax — unused.

    float* out_ctx  = (float*)d_out;                  // B*N*D floats
    float* out_attn = (float*)d_out + 16 * 256 * 256; // B*N*M floats

    float* encP = (float*)d_ws;                       // 4 MB
    float* decS = encP + 16 * 256 * 256;              // 4 MB

    proj_kernel<<<dim3(4, 256), 256, 0, stream>>>(enc, dec, W1, b1, W2, b2, encP, decS);
    attn_kernel<<<dim3(64, 16), 512, 0, stream>>>(enc, encP, decS, vw, out_ctx, out_attn);
}

// Round 3
// 171.468 us; speedup vs baseline: 1.4078x; 1.4078x over previous
//
#include <hip/hip_runtime.h>

// RetrosynthesisAttention, B=16, N=M=D=U=256, fp32.
//   logits[b,n,m] = sum_u v[u]*tanh(ep[m,u]+dp[n,u]) (+const) ; softmax_m ; ctx = attn@enc
//
// tanh(x) = 1 - 2/(exp2(Kx)+1), K=2*log2(e). Constants cancel in softmax.
// exp2(K(ep+dp)) = E*D with E=exp2(K*ep), D=exp2(K*dp) PRECOMPUTED -> no exp in
// the O(B*N*M*U) loop. 4-way rational combining -> one v_rcp per FOUR u's:
//   sum_i v_i/y_i = [(v0y1+v1y0)p23 + (v2y3+v3y2)p01] / (p01*p23),  y=1+E*D
// E stored *2^-16 (y' in [2^-16,2^16], den in [2^-64,2^64]: no overflow);
// the 2^16 scale folds into the logit scale (-2^-15), softmax-invariant.

constexpr float KSC   = 2.8853900817779268f;   // 2*log2(e)
constexpr float LOG2E = 1.4426950408889634f;
constexpr float S16   = 1.52587890625e-05f;    // 2^-16
constexpr float LSC   = -3.0517578125e-05f;    // -2^-15 = -2 * 2^-16

struct F4 { float v[4]; };
__device__ __forceinline__ F4 ld4(const float* p) {
    float4 t = *(const float4*)p;
    F4 r; r.v[0] = t.x; r.v[1] = t.y; r.v[2] = t.z; r.v[3] = t.w; return r;
}

// ---------------- Kernel A: projection GEMMs + exp2 epilogue.
// 64x64 tile, 256 threads, 4x4 micro, K-tile 64. X staged transposed [k][row]
// (pad 65: <=2-way banks); W staged [k][u] (pad 68). All global loads coalesced.
// enc output: encT[b][u][m] = exp2(K*ep - 16)  (transposed, pre-scaled)
// dec output: decE[b*N+n][u] = exp2(K*dp)
__global__ __launch_bounds__(256) void proj_kernel(
    const float* __restrict__ enc, const float* __restrict__ dec,
    const float* __restrict__ W1,  const float* __restrict__ b1,
    const float* __restrict__ W2,  const float* __restrict__ b2,
    float* __restrict__ encT, float* __restrict__ decE)
{
    __shared__ float Xs[64][65];
    __shared__ float Ws[64][68];

    const int tid = threadIdx.x;
    const int tm = tid & 15, tu = tid >> 4;
    const int u0   = blockIdx.x * 64;
    const int row0 = blockIdx.y * 64;          // flat rows 0..8191 (enc|dec)
    const bool is_enc = row0 < 4096;
    const float* X    = is_enc ? enc : dec;
    const float* W    = is_enc ? W1  : W2;
    const float* bias = is_enc ? b1  : b2;
    const int rb = is_enc ? row0 : row0 - 4096;

    float acc[4][4] = {};
    for (int kt = 0; kt < 256; kt += 64) {
        __syncthreads();
        #pragma unroll
        for (int i = 0; i < 4; ++i) {          // X[64 rows][64 k] -> Xs[k][row]
            const int f = tid + (i << 8);
            const int row = f >> 4, kq = (f & 15) << 2;
            F4 x = ld4(&X[(rb + row) * 256 + kt + kq]);
            Xs[kq + 0][row] = x.v[0];
            Xs[kq + 1][row] = x.v[1];
            Xs[kq + 2][row] = x.v[2];
            Xs[kq + 3][row] = x.v[3];
        }
        #pragma unroll
        for (int i = 0; i < 4; ++i) {          // W[64 k][64 u] -> Ws[k][u]
            const int f = tid + (i << 8);
            const int kk = f >> 4, uq = (f & 15) << 2;
            *(float4*)&Ws[kk][uq] = *(const float4*)&W[(kt + kk) * 256 + u0 + uq];
        }
        __syncthreads();
        #pragma unroll 8
        for (int k = 0; k < 64; ++k) {
            const F4 xa = ld4(&Xs[k][tm << 2]);
            const F4 wa = ld4(&Ws[k][tu << 2]);
            #pragma unroll
            for (int i = 0; i < 4; ++i)
                #pragma unroll
                for (int j = 0; j < 4; ++j)
                    acc[i][j] = fmaf(xa.v[i], wa.v[j], acc[i][j]);
        }
    }

    const int ucol = u0 + (tu << 2);
    const F4 bb = ld4(&bias[ucol]);
    if (is_enc) {
        const int b = rb >> 8;
        const int m0 = (rb & 255) + (tm << 2);
        #pragma unroll
        for (int j = 0; j < 4; ++j)
            #pragma unroll
            for (int i = 0; i < 4; ++i) {
                const float z = fmaf(KSC, acc[i][j] + bb.v[j], -16.0f);
                encT[b * 65536 + (ucol + j) * 256 + m0 + i] = __builtin_amdgcn_exp2f(z);
            }
    } else {
        #pragma unroll
        for (int i = 0; i < 4; ++i) {
            const int r = rb + (tm << 2) + i;
            float4 o;
            o.x = __builtin_amdgcn_exp2f(KSC * (acc[i][0] + bb.v[0]));
            o.y = __builtin_amdgcn_exp2f(KSC * (acc[i][1] + bb.v[1]));
            o.z = __builtin_amdgcn_exp2f(KSC * (acc[i][2] + bb.v[2]));
            o.w = __builtin_amdgcn_exp2f(KSC * (acc[i][3] + bb.v[3]));
            *(float4*)&decE[r * 256 + ucol] = o;
        }
    }
}

// ---------------- Kernel B: fused logits + softmax + context.
// Block 512 thr, n-tile 8: half h owns chains t=4h..4h+3; m = tid&255.
// Main loop: per u-quad, 4 coalesced E loads (shared x4 chains), one rcp per
// quad per chain. Grid (32,16) = 512 blocks -> 2 blocks/CU, 16 waves/CU.
__global__ __launch_bounds__(512) void attn_kernel(
    const float* __restrict__ enc,   // [B][M][D]
    const float* __restrict__ encT,  // [B][U][M] = exp2(K*ep-16)
    const float* __restrict__ decE,  // [B*N][U]  = exp2(K*dp)
    const float* __restrict__ vw,    // [U]
    float* __restrict__ out_ctx,     // [B][N][D]
    float* __restrict__ out_attn)    // [B][N][M]
{
    __shared__ float dsD[8][256];
    __shared__ float vws[256];
    __shared__ float attn_s[8][256];
    __shared__ float redm[8][4], reds[8][4];

    const int tid = threadIdx.x;
    const int b   = blockIdx.y;
    const int n0  = blockIdx.x << 3;
    const int h   = tid >> 8;
    const int m   = tid & 255;
    const int t0  = h << 2;

    {   // stage decE rows n0..n0+7 and v
        const float* dsrc = decE + (b * 256 + n0) * 256;
        #pragma unroll
        for (int i = 0; i < 4; ++i)
            ((float*)dsD)[tid + (i << 9)] = dsrc[tid + (i << 9)];
        if (tid < 256) vws[tid] = vw[tid];
    }
    __syncthreads();

    const float* ecol = encT + b * 65536 + m;
    float acc[4] = {0.f, 0.f, 0.f, 0.f};

    #pragma unroll 2
    for (int u0 = 0; u0 < 256; u0 += 4) {
        const float e0 = ecol[(u0 + 0) << 8];
        const float e1 = ecol[(u0 + 1) << 8];
        const float e2 = ecol[(u0 + 2) << 8];
        const float e3 = ecol[(u0 + 3) << 8];
        const F4 vq = ld4(&vws[u0]);
        #pragma unroll
        for (int c = 0; c < 4; ++c) {
            const F4 dq = ld4(&dsD[t0 + c][u0]);
            const float y0 = fmaf(e0, dq.v[0], S16);
            const float y1 = fmaf(e1, dq.v[1], S16);
            const float y2 = fmaf(e2, dq.v[2], S16);
            const float y3 = fmaf(e3, dq.v[3], S16);
            const float p01 = y0 * y1, p23 = y2 * y3;
            const float t01 = fmaf(vq.v[0], y1, vq.v[1] * y0);
            const float t23 = fmaf(vq.v[2], y3, vq.v[3] * y2);
            const float num = fmaf(t01, p23, t23 * p01);
            acc[c] = fmaf(num, __builtin_amdgcn_rcpf(p01 * p23), acc[c]);
        }
    }

    float l[4];
    #pragma unroll
    for (int c = 0; c < 4; ++c) l[c] = acc[c] * LSC;

    // ---- softmax over m (4 waves per half)
    const int lane = tid & 63, wq = (tid >> 6) & 3;
    #pragma unroll
    for (int c = 0; c < 4; ++c) {
        float x = l[c];
        #pragma unroll
        for (int off = 32; off > 0; off >>= 1)
            x = fmaxf(x, __shfl_xor(x, off));
        if (lane == 0) redm[t0 + c][wq] = x;
    }
    __syncthreads();
    float p[4];
    #pragma unroll
    for (int c = 0; c < 4; ++c) {
        const float mx = fmaxf(fmaxf(redm[t0 + c][0], redm[t0 + c][1]),
                               fmaxf(redm[t0 + c][2], redm[t0 + c][3]));
        p[c] = __builtin_amdgcn_exp2f((l[c] - mx) * LOG2E);
    }
    #pragma unroll
    for (int c = 0; c < 4; ++c) {
        float x = p[c];
        #pragma unroll
        for (int off = 32; off > 0; off >>= 1)
            x += __shfl_xor(x, off);
        if (lane == 0) reds[t0 + c][wq] = x;
    }
    __syncthreads();
    #pragma unroll
    for (int c = 0; c < 4; ++c) {
        const float s = (reds[t0 + c][0] + reds[t0 + c][1])
                      + (reds[t0 + c][2] + reds[t0 + c][3]);
        const float w = p[c] * __builtin_amdgcn_rcpf(s);
        attn_s[t0 + c][m] = w;
        out_attn[(b * 256 + n0 + t0 + c) * 256 + m] = w;
    }
    __syncthreads();

    // ---- context: ctx[t][d] = sum_mm attn[t][mm]*enc[b][mm][d], d = m
    const float* eb = enc + b * 65536 + m;
    float cacc[4] = {0.f, 0.f, 0.f, 0.f};
    #pragma unroll 2
    for (int mm = 0; mm < 256; mm += 4) {
        const float g0 = eb[(mm + 0) << 8];
        const float g1 = eb[(mm + 1) << 8];
        const float g2 = eb[(mm + 2) << 8];
        const float g3 = eb[(mm + 3) << 8];
        #pragma unroll
        for (int c = 0; c < 4; ++c) {
            const F4 aq = ld4(&attn_s[t0 + c][mm]);
            cacc[c] = fmaf(aq.v[0], g0, cacc[c]);
            cacc[c] = fmaf(aq.v[1], g1, cacc[c]);
            cacc[c] = fmaf(aq.v[2], g2, cacc[c]);
            cacc[c] = fmaf(aq.v[3], g3, cacc[c]);
        }
    }
    #pragma unroll
    for (int c = 0; c < 4; ++c)
        out_ctx[(b * 256 + n0 + t0 + c) * 256 + m] = cacc[c];
}

extern "C" void kernel_launch(void* const* d_in, const int* in_sizes, int n_in,
                              void* d_out, int out_size, void* d_ws, size_t ws_size,
                              hipStream_t stream) {
    const float* enc = (const float*)d_in[0];
    const float* dec = (const float*)d_in[1];
    const float* W1  = (const float*)d_in[2];
    const float* b1  = (const float*)d_in[3];
    const float* W2  = (const float*)d_in[4];
    const float* b2  = (const float*)d_in[5];
    const float* vw  = (const float*)d_in[6];
    // d_in[7] (v_b) cancels in softmax — unused.

    float* out_ctx  = (float*)d_out;
    float* out_attn = (float*)d_out + 16 * 256 * 256;

    float* encT = (float*)d_ws;                 // 4 MB, exp2(K*ep-16), [b][u][m]
    float* decE = encT + 16 * 256 * 256;        // 4 MB, exp2(K*dp), [b*n][u]

    proj_kernel<<<dim3(4, 128), 256, 0, stream>>>(enc, dec, W1, b1, W2, b2, encT, decE);
    attn_kernel<<<dim3(32, 16), 512, 0, stream>>>(enc, encT, decE, vw, out_ctx, out_attn);
}

// Round 4
// 143.240 us; speedup vs baseline: 1.6852x; 1.1971x over previous
//
#include <hip/hip_runtime.h>

// RetrosynthesisAttention, B=16, N=M=D=U=256, fp32.
// logits[b,n,m] = sum_u v[u]*tanh(ep[m,u]+dp[n,u]) (+const); softmax_m; ctx = attn@enc
//
// tanh(x) = 1 - 2/(exp2(Kx)+1), K=2*log2(e); constants cancel in softmax.
// exp2(K(ep+dp)) = E*D precomputed -> no exp in the O(B*N*M*U) loop.
// v folded into operands: z_u = rcpc(v_u)*(2^-16 + E*D) computed as
// fmaf(E, D*rcpc(v), 2^-16*rcpc(v)); sum_u v_u/y_u = sum_u 1/z_u, combined
// 4-at-a-time: [(z0+z1)p23 + (z2+z3)p01] / (p01*p23) -> ONE rcp per 4 u's.
// E stored *2^-16 (overflow-safe); scale folds into LSC (softmax-invariant).
// encQ layout [b][u/4][m][4]: one coalesced float4 per u-quad in the hot loop.

constexpr float KSC   = 2.8853900817779268f;   // 2*log2(e)
constexpr float LOG2E = 1.4426950408889634f;
constexpr float S16   = 1.52587890625e-05f;    // 2^-16
constexpr float LSC   = -3.0517578125e-05f;    // -2^-15

struct F4 { float v[4]; };
__device__ __forceinline__ F4 ld4(const float* p) {
    float4 t = *(const float4*)p;
    F4 r; r.v[0] = t.x; r.v[1] = t.y; r.v[2] = t.z; r.v[3] = t.w; return r;
}
__device__ __forceinline__ float rcp_clamp(float v) {
    float r = __builtin_amdgcn_rcpf(v);
    return fminf(fmaxf(r, -1e6f), 1e6f);   // guard z^4 overflow for tiny |v|
}

// ---------------- Kernel A: projection GEMMs + exp2 epilogue.
// BM=32 rows, BN=64 u, BK=64, 256 thr, 2x4 micro. Grid (4,256) -> 4 blk/CU.
// X staged transposed [k][row] (stride 33 == 1 mod 32: 2-way banks, free).
// enc out: encQ[b][u/4][m][4] = exp2(K*ep - 16)   (quad layout, float4 stores)
// dec out: decE[n_flat][u]    = exp2(K*dp) * rcpc(v_u)
__global__ __launch_bounds__(256) void proj_kernel(
    const float* __restrict__ enc, const float* __restrict__ dec,
    const float* __restrict__ W1,  const float* __restrict__ b1,
    const float* __restrict__ W2,  const float* __restrict__ b2,
    const float* __restrict__ vw,
    float* __restrict__ encQ, float* __restrict__ decE)
{
    __shared__ float Xs[64][33];   // [k][row]
    __shared__ float Ws[64][68];   // [k][u]

    const int tid = threadIdx.x;
    const int tm = tid & 15, tu = tid >> 4;
    const int u0   = blockIdx.x * 64;
    const int row0 = blockIdx.y * 32;          // flat rows 0..8191 (enc|dec)
    const bool is_enc = row0 < 4096;
    const float* X    = is_enc ? enc : dec;
    const float* W    = is_enc ? W1  : W2;
    const float* bias = is_enc ? b1  : b2;
    const int rb = is_enc ? row0 : row0 - 4096;

    float acc[2][4] = {};
    for (int kt = 0; kt < 256; kt += 64) {
        __syncthreads();
        #pragma unroll
        for (int i = 0; i < 2; ++i) {          // X[32 rows][64 k] -> Xs[k][row]
            const int f = tid + (i << 8);
            const int row = f >> 4, kq = (f & 15) << 2;
            F4 x = ld4(&X[(rb + row) * 256 + kt + kq]);
            Xs[kq + 0][row] = x.v[0];
            Xs[kq + 1][row] = x.v[1];
            Xs[kq + 2][row] = x.v[2];
            Xs[kq + 3][row] = x.v[3];
        }
        #pragma unroll
        for (int i = 0; i < 4; ++i) {          // W[64 k][64 u] -> Ws[k][u]
            const int f = tid + (i << 8);
            const int kk = f >> 4, uq = (f & 15) << 2;
            *(float4*)&Ws[kk][uq] = *(const float4*)&W[(kt + kk) * 256 + u0 + uq];
        }
        __syncthreads();
        #pragma unroll 8
        for (int k = 0; k < 64; ++k) {
            const float xa0 = Xs[k][(tm << 1) | 0];
            const float xa1 = Xs[k][(tm << 1) | 1];
            const F4 wa = ld4(&Ws[k][tu << 2]);
            #pragma unroll
            for (int j = 0; j < 4; ++j) {
                acc[0][j] = fmaf(xa0, wa.v[j], acc[0][j]);
                acc[1][j] = fmaf(xa1, wa.v[j], acc[1][j]);
            }
        }
    }

    const int ucol = u0 + (tu << 2);
    const F4 bb = ld4(&bias[ucol]);
    if (is_enc) {
        const int b  = rb >> 8;
        const int m0 = (rb & 255) + (tm << 1);
        const int uq = ucol >> 2;
        #pragma unroll
        for (int i = 0; i < 2; ++i) {
            float4 o;
            o.x = __builtin_amdgcn_exp2f(fmaf(KSC, acc[i][0] + bb.v[0], -16.f));
            o.y = __builtin_amdgcn_exp2f(fmaf(KSC, acc[i][1] + bb.v[1], -16.f));
            o.z = __builtin_amdgcn_exp2f(fmaf(KSC, acc[i][2] + bb.v[2], -16.f));
            o.w = __builtin_amdgcn_exp2f(fmaf(KSC, acc[i][3] + bb.v[3], -16.f));
            *(float4*)&encQ[b * 65536 + uq * 1024 + (m0 + i) * 4] = o;
        }
    } else {
        const F4 vv = ld4(&vw[ucol]);
        float rv[4];
        #pragma unroll
        for (int j = 0; j < 4; ++j) rv[j] = rcp_clamp(vv.v[j]);
        const int r0 = rb + (tm << 1);
        #pragma unroll
        for (int i = 0; i < 2; ++i) {
            float4 o;
            o.x = __builtin_amdgcn_exp2f(KSC * (acc[i][0] + bb.v[0])) * rv[0];
            o.y = __builtin_amdgcn_exp2f(KSC * (acc[i][1] + bb.v[1])) * rv[1];
            o.z = __builtin_amdgcn_exp2f(KSC * (acc[i][2] + bb.v[2])) * rv[2];
            o.w = __builtin_amdgcn_exp2f(KSC * (acc[i][3] + bb.v[3])) * rv[3];
            *(float4*)&decE[(r0 + i) * 256 + ucol] = o;
        }
    }
}

// ---------------- Kernel B: fused logits + softmax + context.
// 512 thr, n-tile 4 (half h owns chains t0=2h, 2h+1), m = tid&255.
// Grid (64,16)=1024 blocks -> 4 blk/CU, 32 waves/CU theoretical.
// Hot loop per u-quad: 1 coalesced float4 global (encQ), 3 LDS broadcasts,
// 2 x 13-op chains, one rcp per quad per chain.
__global__ __launch_bounds__(512) void attn_kernel(
    const float* __restrict__ enc,   // [B][M][D]
    const float* __restrict__ encQ,  // [b][u/4][m][4] = exp2(K*ep-16)
    const float* __restrict__ decE,  // [n_flat][u]    = exp2(K*dp)*rcpc(v)
    const float* __restrict__ vw,    // [U]
    float* __restrict__ out_ctx,     // [B][N][D]
    float* __restrict__ out_attn)    // [B][N][M]
{
    __shared__ float dsD[4][256];
    __shared__ float vcs[256];
    __shared__ float attn_s[4][256];
    __shared__ float redm[4][4], reds[4][4];

    const int tid = threadIdx.x;
    const int b   = blockIdx.y;
    const int n0  = blockIdx.x << 2;
    const int h   = tid >> 8;
    const int m   = tid & 255;
    const int t0  = h << 1;

    {   // stage decE rows n0..n0+3 (pre-divided by v) and vcs = 2^-16*rcpc(v)
        const float* dsrc = decE + (b * 256 + n0) * 256;
        ((float*)dsD)[tid]       = dsrc[tid];
        ((float*)dsD)[tid + 512] = dsrc[tid + 512];
        if (tid < 256) vcs[tid] = S16 * rcp_clamp(vw[tid]);
    }
    __syncthreads();

    const float* eq = encQ + b * 65536 + (m << 2);
    float acc0 = 0.f, acc1 = 0.f;

    #pragma unroll 2
    for (int q = 0; q < 64; ++q) {
        const F4 E  = ld4(eq + (q << 10));
        const F4 cq = ld4(&vcs[q << 2]);
        {
            const F4 dq = ld4(&dsD[t0][q << 2]);
            const float z0 = fmaf(E.v[0], dq.v[0], cq.v[0]);
            const float z1 = fmaf(E.v[1], dq.v[1], cq.v[1]);
            const float z2 = fmaf(E.v[2], dq.v[2], cq.v[2]);
            const float z3 = fmaf(E.v[3], dq.v[3], cq.v[3]);
            const float p01 = z0 * z1, p23 = z2 * z3;
            const float n01 = z0 + z1, n23 = z2 + z3;
            const float num = fmaf(n01, p23, n23 * p01);
            acc0 = fmaf(num, __builtin_amdgcn_rcpf(p01 * p23), acc0);
        }
        {
            const F4 dq = ld4(&dsD[t0 + 1][q << 2]);
            const float z0 = fmaf(E.v[0], dq.v[0], cq.v[0]);
            const float z1 = fmaf(E.v[1], dq.v[1], cq.v[1]);
            const float z2 = fmaf(E.v[2], dq.v[2], cq.v[2]);
            const float z3 = fmaf(E.v[3], dq.v[3], cq.v[3]);
            const float p01 = z0 * z1, p23 = z2 * z3;
            const float n01 = z0 + z1, n23 = z2 + z3;
            const float num = fmaf(n01, p23, n23 * p01);
            acc1 = fmaf(num, __builtin_amdgcn_rcpf(p01 * p23), acc1);
        }
    }

    const float l0 = acc0 * LSC, l1 = acc1 * LSC;

    // ---- softmax over m (4 waves per half)
    const int lane = tid & 63, wq = (tid >> 6) & 3;
    float x0 = l0, x1 = l1;
    #pragma unroll
    for (int off = 32; off > 0; off >>= 1) {
        x0 = fmaxf(x0, __shfl_xor(x0, off));
        x1 = fmaxf(x1, __shfl_xor(x1, off));
    }
    if (lane == 0) { redm[t0][wq] = x0; redm[t0 + 1][wq] = x1; }
    __syncthreads();
    const float mx0 = fmaxf(fmaxf(redm[t0][0], redm[t0][1]),
                            fmaxf(redm[t0][2], redm[t0][3]));
    const float mx1 = fmaxf(fmaxf(redm[t0 + 1][0], redm[t0 + 1][1]),
                            fmaxf(redm[t0 + 1][2], redm[t0 + 1][3]));
    float p0 = __builtin_amdgcn_exp2f((l0 - mx0) * LOG2E);
    float p1 = __builtin_amdgcn_exp2f((l1 - mx1) * LOG2E);
    float s0 = p0, s1 = p1;
    #pragma unroll
    for (int off = 32; off > 0; off >>= 1) {
        s0 += __shfl_xor(s0, off);
        s1 += __shfl_xor(s1, off);
    }
    if (lane == 0) { reds[t0][wq] = s0; reds[t0 + 1][wq] = s1; }
    __syncthreads();
    const float sum0 = (reds[t0][0] + reds[t0][1]) + (reds[t0][2] + reds[t0][3]);
    const float sum1 = (reds[t0 + 1][0] + reds[t0 + 1][1]) + (reds[t0 + 1][2] + reds[t0 + 1][3]);
    const float w0 = p0 * __builtin_amdgcn_rcpf(sum0);
    const float w1 = p1 * __builtin_amdgcn_rcpf(sum1);
    attn_s[t0][m]     = w0;
    attn_s[t0 + 1][m] = w1;
    out_attn[(b * 256 + n0 + t0) * 256 + m]     = w0;
    out_attn[(b * 256 + n0 + t0 + 1) * 256 + m] = w1;
    __syncthreads();

    // ---- context: ctx[t][d] = sum_mm attn[t][mm]*enc[b][mm][d], d = m
    const float* eb = enc + b * 65536 + m;
    float c0 = 0.f, c1 = 0.f;
    #pragma unroll 2
    for (int mm = 0; mm < 256; mm += 4) {
        const float g0 = eb[(mm + 0) << 8];
        const float g1 = eb[(mm + 1) << 8];
        const float g2 = eb[(mm + 2) << 8];
        const float g3 = eb[(mm + 3) << 8];
        const F4 a0 = ld4(&attn_s[t0][mm]);
        const F4 a1 = ld4(&attn_s[t0 + 1][mm]);
        c0 = fmaf(a0.v[0], g0, c0); c1 = fmaf(a1.v[0], g0, c1);
        c0 = fmaf(a0.v[1], g1, c0); c1 = fmaf(a1.v[1], g1, c1);
        c0 = fmaf(a0.v[2], g2, c0); c1 = fmaf(a1.v[2], g2, c1);
        c0 = fmaf(a0.v[3], g3, c0); c1 = fmaf(a1.v[3], g3, c1);
    }
    out_ctx[(b * 256 + n0 + t0) * 256 + m]     = c0;
    out_ctx[(b * 256 + n0 + t0 + 1) * 256 + m] = c1;
}

extern "C" void kernel_launch(void* const* d_in, const int* in_sizes, int n_in,
                              void* d_out, int out_size, void* d_ws, size_t ws_size,
                              hipStream_t stream) {
    const float* enc = (const float*)d_in[0];
    const float* dec = (const float*)d_in[1];
    const float* W1  = (const float*)d_in[2];
    const float* b1  = (const float*)d_in[3];
    const float* W2  = (const float*)d_in[4];
    const float* b2  = (const float*)d_in[5];
    const float* vw  = (const float*)d_in[6];
    // d_in[7] (v_b) cancels in softmax — unused.

    float* out_ctx  = (float*)d_out;
    float* out_attn = (float*)d_out + 16 * 256 * 256;

    float* encQ = (float*)d_ws;                 // 4 MB
    float* decE = encQ + 16 * 256 * 256;        // 4 MB

    proj_kernel<<<dim3(4, 256), 256, 0, stream>>>(enc, dec, W1, b1, W2, b2, vw, encQ, decE);
    attn_kernel<<<dim3(64, 16), 512, 0, stream>>>(enc, encQ, decE, vw, out_ctx, out_attn);
}